// Round 3
// baseline (402.417 us; speedup 1.0000x reference)
//
#include <hip/hip_runtime.h>

typedef unsigned short u16;
typedef unsigned int   u32;
typedef _Float16 f16;
typedef f16 h2 __attribute__((ext_vector_type(2)));
typedef f16 h4 __attribute__((ext_vector_type(4)));
typedef f16 h8 __attribute__((ext_vector_type(8)));

#define T_    120
#define D_    64
#define DOUT_ 31
#define KROW_ 68    // f16/row: 136B, 8B-aligned
#define VROW_ 132   // f16/row: 264B, 8B-aligned

#if defined(__has_builtin)
#if __has_builtin(__builtin_amdgcn_fdot2)
#define DOT2(a,b,c) __builtin_amdgcn_fdot2((a),(b),(c),false)
#endif
#endif
#ifndef DOT2
#define DOT2(a,b,c) ((float)(a).x*(float)(b).x + ((float)(a).y*(float)(b).y + (c)))
#endif
#define SHV(x,i,j) __builtin_shufflevector((x),(x),(i),(j))

__device__ __forceinline__ h2 pk(float a, float b){
#if defined(__has_builtin) && __has_builtin(__builtin_amdgcn_cvt_pkrtz)
  return __builtin_bit_cast(h2, __builtin_amdgcn_cvt_pkrtz(a, b));
#else
  h2 r; r.x = (f16)a; r.y = (f16)b; return r;
#endif
}
__device__ __forceinline__ float b2f(u16 u){ return __uint_as_float(((u32)u) << 16); }
__device__ __forceinline__ float2 bp2(u32 u){
  float2 r; r.x = __uint_as_float(u << 16); r.y = __uint_as_float(u & 0xffff0000u); return r;
}
__device__ __forceinline__ u16 f2bu(float f){
  u32 u = __float_as_uint(f);
  u32 r = u + 0x7fffu + ((u >> 16) & 1u);
  return (u16)(r >> 16);
}
__device__ __forceinline__ u16 f2h16(float x){
  f16 v = (f16)x; u16 r; __builtin_memcpy(&r, &v, 2); return r;
}
__device__ __forceinline__ float fast_rcp(float x){
#if defined(__has_builtin) && __has_builtin(__builtin_amdgcn_rcpf)
  return __builtin_amdgcn_rcpf(x);
#else
  return 1.f / x;
#endif
}
#define WSYNC() do{ __asm__ __volatile__("" ::: "memory"); __builtin_amdgcn_wave_barrier(); }while(0)

__device__ __forceinline__ float dpp_sum(float x){
  int t;
  t = __builtin_amdgcn_update_dpp(0, __float_as_int(x), 0x111, 0xf, 0xf, true); x += __int_as_float(t);
  t = __builtin_amdgcn_update_dpp(0, __float_as_int(x), 0x112, 0xf, 0xf, true); x += __int_as_float(t);
  t = __builtin_amdgcn_update_dpp(0, __float_as_int(x), 0x114, 0xf, 0xf, true); x += __int_as_float(t);
  t = __builtin_amdgcn_update_dpp(0, __float_as_int(x), 0x118, 0xf, 0xf, true); x += __int_as_float(t);
  t = __builtin_amdgcn_update_dpp(0, __float_as_int(x), 0x142, 0xf, 0xf, true); x += __int_as_float(t);
  t = __builtin_amdgcn_update_dpp(0, __float_as_int(x), 0x143, 0xf, 0xf, true); x += __int_as_float(t);
  return __int_as_float(__builtin_amdgcn_readlane(__float_as_int(x), 63));
}
__device__ __forceinline__ float dpp_max_pos(float x){   // requires true max > 0
  int t;
  t = __builtin_amdgcn_update_dpp(0, __float_as_int(x), 0x111, 0xf, 0xf, true); x = fmaxf(x, __int_as_float(t));
  t = __builtin_amdgcn_update_dpp(0, __float_as_int(x), 0x112, 0xf, 0xf, true); x = fmaxf(x, __int_as_float(t));
  t = __builtin_amdgcn_update_dpp(0, __float_as_int(x), 0x114, 0xf, 0xf, true); x = fmaxf(x, __int_as_float(t));
  t = __builtin_amdgcn_update_dpp(0, __float_as_int(x), 0x118, 0xf, 0xf, true); x = fmaxf(x, __int_as_float(t));
  t = __builtin_amdgcn_update_dpp(0, __float_as_int(x), 0x142, 0xf, 0xf, true); x = fmaxf(x, __int_as_float(t));
  t = __builtin_amdgcn_update_dpp(0, __float_as_int(x), 0x143, 0xf, 0xf, true); x = fmaxf(x, __int_as_float(t));
  return __int_as_float(__builtin_amdgcn_readlane(__float_as_int(x), 63));
}
__device__ __forceinline__ float pe_val(int row, int i){
  const float coef = -0.28782313662425574f; // -ln(10000)/32
  int p = row % 10;
  float dv  = __expf((float)(i >> 1) * coef);
  float ang = (float)p * dv;
  return (i & 1) ? __cosf(ang) : __sinf(ang);
}
__device__ __forceinline__ void loadrow32(h2* dst, const float* row){
  #pragma unroll
  for (int r = 0; r < 16; ++r){
    float4 f = ((const float4*)row)[r];
    dst[2*r]   = pk(f.x, f.y);
    dst[2*r+1] = pk(f.z, f.w);
  }
}

// ---------- kernel PRE: blocks 0-119: mem+cross; block 120: bf16 prep + M=Wm@Wr fusion ----------
__global__ __launch_bounds__(256) void k_pre(const float* __restrict__ audio,
                                             const float* __restrict__ Wa, const float* __restrict__ ba,
                                             const float* __restrict__ Wv2, const float* __restrict__ bv2,
                                             const float* __restrict__ Wo2, const float* __restrict__ bo2,
                                             const float* __restrict__ Wo, const float* __restrict__ W1,
                                             const float* __restrict__ W2, const float* __restrict__ Wr,
                                             const float* __restrict__ Wm, const float* __restrict__ br,
                                             const float* __restrict__ bm,
                                             float* __restrict__ cross, float* __restrict__ Ms,
                                             float* __restrict__ bMv,
                                             u16* __restrict__ wob, u16* __restrict__ w1b,
                                             u16* __restrict__ w2b, u16* __restrict__ wrb){
  const int b = blockIdx.x, tid = threadIdx.x;
  if (b == 120){
    for (int i = tid; i < 4096; i += 256) wob[i] = f2bu(Wo[i]);
    for (int i = tid; i < 8192; i += 256){ w1b[i] = f2bu(W1[i]); w2b[i] = f2bu(W2[i]); }
    for (int i = tid; i < 1984; i += 256) wrb[i] = f2bu(Wr[i]);
    for (int idx = tid; idx < 4096; idx += 256){
      int d = idx >> 6, e = idx & 63;
      float acc = 0.f;
      #pragma unroll
      for (int j = 0; j < 31; ++j) acc += Wm[d*31 + j] * Wr[j*64 + e];
      Ms[idx] = acc;
    }
    if (tid < 64){
      float acc = bm[tid];
      #pragma unroll
      for (int j = 0; j < 31; ++j) acc += Wm[tid*31 + j] * br[j];
      bMv[tid] = acc;
    }
    return;
  }
  __shared__ float ash[1024];
  __shared__ float msh[64], tsh[64];
  for (int i = tid; i < 1024; i += 256) ash[i] = audio[b*1024 + i];
  __syncthreads();
  const int w = tid >> 6, lane = tid & 63;
  for (int d = w*16; d < w*16 + 16; ++d){
    const float4* row = (const float4*)(Wa + d*1024);
    float acc = 0.f;
    #pragma unroll
    for (int m = 0; m < 4; ++m){
      float4 wp = row[lane + 64*m];
      int j = 4*(lane + 64*m);
      acc += wp.x*ash[j] + wp.y*ash[j+1] + wp.z*ash[j+2] + wp.w*ash[j+3];
    }
    acc = dpp_sum(acc);
    if (lane == 0) msh[d] = acc + ba[d];
  }
  __syncthreads();
  if (tid < 64){
    const float4* r1 = (const float4*)(Wv2 + tid*64);
    float a = bv2[tid];
    #pragma unroll
    for (int j = 0; j < 16; ++j){ float4 p = r1[j]; a += p.x*msh[4*j] + p.y*msh[4*j+1] + p.z*msh[4*j+2] + p.w*msh[4*j+3]; }
    tsh[tid] = a;
  }
  __syncthreads();
  if (tid < 64){
    const float4* r2 = (const float4*)(Wo2 + tid*64);
    float c = bo2[tid];
    #pragma unroll
    for (int j = 0; j < 16; ++j){ float4 p = r2[j]; c += p.x*tsh[4*j] + p.y*tsh[4*j+1] + p.z*tsh[4*j+2] + p.w*tsh[4*j+3]; }
    cross[b*64 + tid] = c;
  }
}

// ---------- kernel SCAN: 2 waves, wave-parallel phases, 5 barriers/iter ----------
//  P1 (both):  wave h lanes 0-31 -> q[h-half], lanes 32-63 -> k_t[h-half]; WSYNC.
//  P2 (both):  wave0 also v_t (reg-x); each wave: own head's scores + exp.   BARRIER
//  P4 (both):  per-head denom+rcp; PV partial (w0: 0-63, w1: 64-119);
//              each wave dots Wo vs OWN partial -> (lo,hi) unscaled.
//              wave1 publishes lo/hi + inv1.                                 BARRIER
//  P5 (w0):    sa combine -> LN1 -> +cross -> LN2 -> h2h/h2f.                BARRIER
//  P6 (both):  FFN1 (w0: W1 rows 0-63 via D; w1: rows 64-127 via B) -> fsh.  BARRIER
//  P7 (w1):    FFN2 (D,F) -> LN3 folded into M' matvec (E) -> x_{t+1}.       BARRIER
__global__ __launch_bounds__(128, 1) void k_scan(
    const float* __restrict__ objW,
    const float* __restrict__ Wq, const float* __restrict__ bq,
    const float* __restrict__ Wk, const float* __restrict__ bk,
    const float* __restrict__ Wv, const float* __restrict__ bv,
    const float* __restrict__ Wo, const float* __restrict__ bo,
    const float* __restrict__ g1, const float* __restrict__ be1,
    const float* __restrict__ g2, const float* __restrict__ be2,
    const float* __restrict__ g3, const float* __restrict__ be3,
    const float* __restrict__ W1, const float* __restrict__ c1,
    const float* __restrict__ W2, const float* __restrict__ c2,
    const float* __restrict__ Ms, const float* __restrict__ bMv,
    const float* __restrict__ cross,
    u16* __restrict__ xw16, u16* __restrict__ Kw16, u16* __restrict__ Vw16)
{
  __shared__ __align__(16) f16 KcS[128*KROW_];   // rows 119..127 stay zero
  __shared__ __align__(16) f16 VcS[D_*VROW_];
  __shared__ __align__(16) f16 xwS[T_*D_];       // x history (f16)
  __shared__ __align__(16) f16 sch[256];
  __shared__ __align__(16) f16 xh[64], qh[64], h2h[64], h3h[64];
  __shared__ __align__(16) f16 at0h[64], at1h[64];   // per-wave scratch
  __shared__ __align__(16) f16 fsh[128];
  __shared__ float sa1lo[64], sa1hi[64];
  __shared__ float h2f[64], xf[64];
  __shared__ float invSh;                            // head1 inverse denom
  __shared__ float pe_tab[640];

  const int tid = threadIdx.x;
  const int i = tid & 63;
  const int hh = tid >> 6;      // wave index == head index
  const bool w0 = tid < 64;

  // register weights:
  //  both : A = (i<32 ? Wq row hh*32+i : Wk row hh*32+(i-32)),  C = Wo row i
  //  wave0: B = Wv row i, D = W1 row i
  //  wave1: B = W1 row 64+i, D = W2 row i cols 0-63, F = W2 row i cols 64-127,
  //         E = (Ms.*g3) row i
  h2 A[32], B[32], C[32], D[32], E[32], F[32];
  float biasA=0.f, biasB=0.f, bo_r=0.f, c1r=0.f, c2_r=0.f, cls_r=0.f;
  float g1r=0.f,b1r=0.f,g2r=0.f,b2r=0.f;
  float mg_r=0.f, u_r=0.f;      // wave1: row-sum of Ms.*g3, and Ms.be3 + bMv + style

  {
    const int qi = hh*32 + (i & 31);
    if (i < 32){ loadrow32(A, Wq + qi*64); biasA = bq[qi]; }
    else       { loadrow32(A, Wk + qi*64); biasA = bk[qi]; }
    loadrow32(C, Wo + i*64);
  }
  if (w0){
    loadrow32(B, Wv + i*64);
    loadrow32(D, W1 + i*64);
    biasB = bv[i]; c1r = c1[i];
    bo_r = bo[i];
    g1r = g1[i]; b1r = be1[i]; g2r = g2[i]; b2r = be2[i];
    cls_r = cross[119*64 + i];
  } else {
    loadrow32(B, W1 + (64+i)*64);
    loadrow32(D, W2 + i*128);
    loadrow32(F, W2 + i*128 + 64);
    {
      const float4* mr  = (const float4*)(Ms + i*64);
      const float4* gv  = (const float4*)g3;
      const float4* b3v = (const float4*)be3;
      float mg = 0.f, mb = 0.f;
      #pragma unroll
      for (int r = 0; r < 16; ++r){
        float4 f = mr[r], g = gv[r], b = b3v[r];
        float e0 = f.x*g.x, e1 = f.y*g.y, e2 = f.z*g.z, e3 = f.w*g.w;
        E[2*r]   = pk(e0, e1);
        E[2*r+1] = pk(e2, e3);
        mg += (e0+e1)+(e2+e3);
        mb += f.x*b.x + f.y*b.y + f.z*b.z + f.w*b.w;
      }
      mg_r = mg;
      u_r  = bMv[i] + objW[i*5] + mb;
    }
    c1r = c1[64+i]; c2_r = c2[i];
  }
  { u32* p = (u32*)KcS; for (int idx = tid; idx < 128*KROW_/2; idx += 128) p[idx] = 0; }
  { u32* p = (u32*)VcS; for (int idx = tid; idx < D_*VROW_/2;  idx += 128) p[idx] = 0; }
  for (int idx = tid; idx < 640; idx += 128) pe_tab[idx] = pe_val(idx >> 6, idx & 63);
  if (!w0){
    float x0 = objW[i*5] + pe_val(0, i);
    xf[i] = x0; xh[i] = (f16)x0; xwS[i] = (f16)x0;
  }
  __syncthreads();

  int pp = 1;  // (t+1) % 10
  for (int t = 0; t < T_-1; ++t){
    float e0r, e1r, inv_w, lo_w = 0.f, hi_w = 0.f;
    h8 xr[8];
    // ---- P1: each wave computes its own q-half + k-half ----
    {
      const h8* xv = (const h8*)xh;
      #pragma unroll
      for (int r = 0; r < 8; ++r) xr[r] = xv[r];
      float a0=biasA,a1=0.f,a2=0.f,a3=0.f;
      #pragma unroll
      for (int r = 0; r < 8; ++r){
        h8 x = xr[r];
        a0 = DOT2(A[4*r+0], SHV(x,0,1), a0);
        a1 = DOT2(A[4*r+1], SHV(x,2,3), a1);
        a2 = DOT2(A[4*r+2], SHV(x,4,5), a2);
        a3 = DOT2(A[4*r+3], SHV(x,6,7), a3);
      }
      float qk = (a0+a1)+(a2+a3);
      f16* dst = (i < 32) ? (qh + hh*32 + i) : (KcS + t*KROW_ + hh*32 + (i - 32));
      *dst = (f16)qk;
    }
    WSYNC();
    // ---- P2: wave0 v in read-shadow; each wave: its head's scores + exp ----
    {
      if (w0){
        float v0=biasB,v1=0.f,v2=0.f,v3=0.f;
        #pragma unroll
        for (int r = 0; r < 8; ++r){
          h8 x = xr[r];
          v0 = DOT2(B[4*r+0], SHV(x,0,1), v0); v1 = DOT2(B[4*r+1], SHV(x,2,3), v1);
          v2 = DOT2(B[4*r+2], SHV(x,4,5), v2); v3 = DOT2(B[4*r+3], SHV(x,6,7), v3);
        }
        VcS[i*VROW_ + t] = (f16)((v0+v1)+(v2+v3));
      }
      const int j = i;
      const h8* qv = (const h8*)(qh + hh*32);
      const h4* k0 = (const h4*)(KcS + j*KROW_ + hh*32);
      const h4* k1 = (const h4*)(KcS + (j+64)*KROW_ + hh*32);
      float d0a=0.f,d0b=0.f,d1a=0.f,d1b=0.f;
      #pragma unroll
      for (int r = 0; r < 4; ++r){
        h8 q = qv[r];
        h4 ka = k0[2*r], kb = k0[2*r+1], kc = k1[2*r], kd = k1[2*r+1];
        d0a = DOT2(SHV(ka,0,1), SHV(q,0,1), d0a);
        d0b = DOT2(SHV(ka,2,3), SHV(q,2,3), d0b);
        d0a = DOT2(SHV(kb,0,1), SHV(q,4,5), d0a);
        d0b = DOT2(SHV(kb,2,3), SHV(q,6,7), d0b);
        d1a = DOT2(SHV(kc,0,1), SHV(q,0,1), d1a);
        d1b = DOT2(SHV(kc,2,3), SHV(q,2,3), d1b);
        d1a = DOT2(SHV(kd,0,1), SHV(q,4,5), d1a);
        d1b = DOT2(SHV(kd,2,3), SHV(q,6,7), d1b);
      }
      float d0 = d0a + d0b, d1 = d1a + d1b;
      const float slope = hh ? 0.00390625f : 0.0625f;
      int r0 = (t - j) / 10, r1 = (t - j - 64) / 10;
      float s0 = d0*0.17677669529663687f - slope*(float)r0;
      float s1 = d1*0.17677669529663687f - slope*(float)r1;
      e0r = (j      <= t) ? __expf(fminf(s0, 8.f)) : 0.f;
      e1r = (j + 64 <= t) ? __expf(fminf(s1, 8.f)) : 0.f;
      sch[hh*128 + j]      = (f16)e0r;
      sch[hh*128 + j + 64] = (f16)e1r;
    }
    __syncthreads();
    // ---- P4: per-head denom; PV partial; OWN Wo dot -> (lo,hi) unscaled ----
    {
      float den = dpp_sum(e0r + e1r);
      inv_w = fast_rcp(den);
      if (tid == 64) invSh = inv_w;        // wave1 publishes head1 inv
      if (w0 || t >= 64){
        const int hd = i >> 5;
        const h8* av = (const h8*)(sch + hd*128) + (w0 ? 0 : 8);
        const h4* vv = (const h4*)(VcS + i*VROW_) + (w0 ? 0 : 16);
        float p0=0.f,p1=0.f,p2=0.f,p3=0.f;
        #pragma unroll
        for (int r = 0; r < 8; ++r){
          h8 a = av[r];
          h4 va = vv[2*r], vb = vv[2*r+1];
          p0 = DOT2(SHV(va,0,1), SHV(a,0,1), p0);
          p1 = DOT2(SHV(va,2,3), SHV(a,2,3), p1);
          p2 = DOT2(SHV(vb,0,1), SHV(a,4,5), p2);
          p3 = DOT2(SHV(vb,2,3), SHV(a,6,7), p3);
        }
        float p = (p0+p1)+(p2+p3);
        f16* ath = w0 ? at0h : at1h;
        ath[i] = (f16)p;
        WSYNC();
        const h8* pv = (const h8*)ath;
        float l0=0.f,l1=0.f,q0=0.f,q1=0.f;
        #pragma unroll
        for (int r = 0; r < 4; ++r){
          h8 x = pv[r];
          l0 = DOT2(C[4*r+0], SHV(x,0,1), l0); l1 = DOT2(C[4*r+1], SHV(x,2,3), l1);
          l0 = DOT2(C[4*r+2], SHV(x,4,5), l0); l1 = DOT2(C[4*r+3], SHV(x,6,7), l1);
        }
        #pragma unroll
        for (int r = 4; r < 8; ++r){
          h8 x = pv[r];
          q0 = DOT2(C[4*r+0], SHV(x,0,1), q0); q1 = DOT2(C[4*r+1], SHV(x,2,3), q1);
          q0 = DOT2(C[4*r+2], SHV(x,4,5), q0); q1 = DOT2(C[4*r+3], SHV(x,6,7), q1);
        }
        lo_w = l0 + l1;  hi_w = q0 + q1;
      }
      if (!w0){ sa1lo[i] = lo_w; sa1hi[i] = hi_w; }
    }
    __syncthreads();
    // ---- P5 (wave0): sa combine -> LN1 -> +cross -> LN2 ----
    if (w0){
      float xfv = xf[i];
      float inv1 = invSh;
      float lo1 = 0.f, hi1 = 0.f;
      if (t >= 64){ lo1 = sa1lo[i]; hi1 = sa1hi[i]; }
      float sa = bo_r + inv_w*(lo_w + lo1) + inv1*(hi_w + hi1);
      float y = xfv + sa;
      float s = dpp_sum(y), s2 = dpp_sum(y*y);
      float m = s*(1.f/64.f), var = fmaxf(s2*(1.f/64.f) - m*m, 0.f);
      float h1 = (y - m)*rsqrtf(var + 1e-5f)*g1r + b1r;
      float z = h1 + cls_r;
      float sz = dpp_sum(z), sz2 = dpp_sum(z*z);
      float mz = sz*(1.f/64.f), vz = fmaxf(sz2*(1.f/64.f) - mz*mz, 0.f);
      float h2v = (z - mz)*rsqrtf(vz + 1e-5f)*g2r + b2r;
      h2h[i] = (f16)h2v;
      h2f[i] = h2v;
    }
    __syncthreads();
    // ---- P6: FFN1 both waves (wave0: D = W1 rows 0..63; wave1: B = rows 64..127) ----
    {
      const h8* hv = (const h8*)h2h;
      float a0=c1r, a1=0.f, a2=0.f, a3=0.f;
      if (w0){
        #pragma unroll
        for (int r = 0; r < 8; ++r){
          h8 x = hv[r];
          a0 = DOT2(D[4*r+0], SHV(x,0,1), a0);
          a1 = DOT2(D[4*r+1], SHV(x,2,3), a1);
          a2 = DOT2(D[4*r+2], SHV(x,4,5), a2);
          a3 = DOT2(D[4*r+3], SHV(x,6,7), a3);
        }
      } else {
        #pragma unroll
        for (int r = 0; r < 8; ++r){
          h8 x = hv[r];
          a0 = DOT2(B[4*r+0], SHV(x,0,1), a0);
          a1 = DOT2(B[4*r+1], SHV(x,2,3), a1);
          a2 = DOT2(B[4*r+2], SHV(x,4,5), a2);
          a3 = DOT2(B[4*r+3], SHV(x,6,7), a3);
        }
      }
      fsh[tid] = (f16)fmaxf((a0+a1)+(a2+a3), 0.f);
    }
    __syncthreads();
    // ---- P7 (wave1): FFN2 (D,F) ; LN3 folded into M' matvec (E) ; + pe ----
    if (!w0){
      float pe_c  = pe_tab[pp*64 + i];
      float h2v_s = h2f[i];
      const h8* fv = (const h8*)fsh;
      float a0=c2_r, a1=0.f, a2=0.f, a3=0.f;
      #pragma unroll
      for (int r = 0; r < 8; ++r){
        h8 x = fv[r];
        a0 = DOT2(D[4*r+0], SHV(x,0,1), a0);
        a1 = DOT2(D[4*r+1], SHV(x,2,3), a1);
        a2 = DOT2(D[4*r+2], SHV(x,4,5), a2);
        a3 = DOT2(D[4*r+3], SHV(x,6,7), a3);
      }
      #pragma unroll
      for (int r = 0; r < 8; ++r){
        h8 x = fv[8+r];
        a0 = DOT2(F[4*r+0], SHV(x,0,1), a0);
        a1 = DOT2(F[4*r+1], SHV(x,2,3), a1);
        a2 = DOT2(F[4*r+2], SHV(x,4,5), a2);
        a3 = DOT2(F[4*r+3], SHV(x,6,7), a3);
      }
      float y3 = h2v_s + (a0+a1)+(a2+a3);
      h3h[i] = (f16)y3;           // pre-norm y3; LN3 stats overlap the re-read below
      WSYNC();
      const h8* yv3 = (const h8*)h3h;
      h8 yr[8];
      #pragma unroll
      for (int r = 0; r < 8; ++r) yr[r] = yv3[r];
      float s3 = dpp_sum(y3), s32 = dpp_sum(y3*y3);
      float m3 = s3*(1.f/64.f), v3 = fmaxf(s32*(1.f/64.f) - m3*m3, 0.f);
      float invs = rsqrtf(v3 + 1e-5f);
      float m0=0.f, m1=0.f, m2=0.f, mm3=0.f;
      #pragma unroll
      for (int r = 0; r < 8; ++r){
        h8 x = yr[r];
        m0 = DOT2(E[4*r+0], SHV(x,0,1), m0);
        m1 = DOT2(E[4*r+1], SHV(x,2,3), m1);
        m2 = DOT2(E[4*r+2], SHV(x,4,5), m2);
        mm3 = DOT2(E[4*r+3], SHV(x,6,7), mm3);
      }
      float xn = ((m0+m1)+(m2+mm3))*invs + (u_r - m3*invs*mg_r) + pe_c;
      xf[i] = xn;
      xh[i] = (f16)xn;
      xwS[(t+1)*64 + i] = (f16)xn;
    }
    __syncthreads();
    pp = (pp == 9) ? 0 : pp + 1;
  }
  // ---- epilogue: k,v for row 119 directly to global f16 ----
  {
    const h8* xv = (const h8*)xh;
    h8 xr[8];
    #pragma unroll
    for (int r = 0; r < 8; ++r) xr[r] = xv[r];
    if (w0){
      float v0=biasB,v1=0.f,v2=0.f,v3=0.f;
      #pragma unroll
      for (int r = 0; r < 8; ++r){
        h8 x = xr[r];
        v0 = DOT2(B[4*r+0], SHV(x,0,1), v0);
        v1 = DOT2(B[4*r+1], SHV(x,2,3), v1);
        v2 = DOT2(B[4*r+2], SHV(x,4,5), v2);
        v3 = DOT2(B[4*r+3], SHV(x,6,7), v3);
      }
      Vw16[119*64 + i] = f2h16((v0+v1)+(v2+v3));
    }
    if (i >= 32){
      float k0=biasA,k1=0.f,k2=0.f,k3=0.f;
      #pragma unroll
      for (int r = 0; r < 8; ++r){
        h8 x = xr[r];
        k0 = DOT2(A[4*r+0], SHV(x,0,1), k0);
        k1 = DOT2(A[4*r+1], SHV(x,2,3), k1);
        k2 = DOT2(A[4*r+2], SHV(x,4,5), k2);
        k3 = DOT2(A[4*r+3], SHV(x,6,7), k3);
      }
      Kw16[119*64 + hh*32 + (i-32)] = f2h16((k0+k1)+(k2+k3));
    }
  }
  // ---- dump LDS histories (rows 0..118 K/V, all x) ----
  {
    const u16* kc = (const u16*)KcS;
    const u16* vc = (const u16*)VcS;
    for (int idx = tid; idx < 119*64; idx += 128){
      int t_ = idx >> 6, d = idx & 63;
      Kw16[idx] = kc[t_*KROW_ + d];
      Vw16[idx] = vc[d*VROW_ + t_];
    }
    const u32* xs32 = (const u32*)xwS;
    for (int idx = tid; idx < T_*D_/2; idx += 128) ((u32*)xw16)[idx] = xs32[idx];
  }
}

// ---------- kernel FINAL: full pass, one block per row (f16 x/K/V inputs) ----------
__global__ __launch_bounds__(128) void k_final(
    const float* __restrict__ Wq, const float* __restrict__ bq, const float* __restrict__ bo,
    const float* __restrict__ g1, const float* __restrict__ be1,
    const float* __restrict__ g2, const float* __restrict__ be2,
    const float* __restrict__ g3, const float* __restrict__ be3,
    const float* __restrict__ c1, const float* __restrict__ c2, const float* __restrict__ br,
    const u16* __restrict__ wo_b, const u16* __restrict__ w1_b,
    const u16* __restrict__ w2_b, const u16* __restrict__ wr_b,
    const float* __restrict__ cross, const u16* __restrict__ xw16,
    const u16* __restrict__ Kw16, const u16* __restrict__ Vw16,
    float* __restrict__ out)
{
  __shared__ float xs[64], qs[64], at[64], h2s[64], h3s[64], fs[128], sc[256];
  const int irow = blockIdx.x, tid = threadIdx.x;
  const f16* xp = (const f16*)xw16;
  const f16* kp = (const f16*)Kw16;
  const f16* vp = (const f16*)Vw16;
  if (tid < 64) xs[tid] = (float)xp[irow*64 + tid];
  __syncthreads();
  if (tid < 64){
    const float4* wr_ = (const float4*)(Wq + tid*64);
    float acc = bq[tid];
    #pragma unroll
    for (int j = 0; j < 16; ++j){ float4 w = wr_[j]; acc += w.x*xs[4*j] + w.y*xs[4*j+1] + w.z*xs[4*j+2] + w.w*xs[4*j+3]; }
    qs[tid] = acc;
  }
  __syncthreads();
  {
    const int h = tid >> 6, j = tid & 63;
    const float* qh_ = qs + h*32;
    float d0 = 0.f, d1 = 0.f;
    const h4* k0 = (const h4*)(kp + j*64 + h*32);
    #pragma unroll
    for (int w = 0; w < 8; ++w){
      h4 p = k0[w];
      d0 += (float)p.x*qh_[4*w] + (float)p.y*qh_[4*w+1] + (float)p.z*qh_[4*w+2] + (float)p.w*qh_[4*w+3];
    }
    if (j < 56){
      const h4* k1 = (const h4*)(kp + (j+64)*64 + h*32);
      #pragma unroll
      for (int w = 0; w < 8; ++w){
        h4 p = k1[w];
        d1 += (float)p.x*qh_[4*w] + (float)p.y*qh_[4*w+1] + (float)p.z*qh_[4*w+2] + (float)p.w*qh_[4*w+3];
      }
    }
    const float slope = h ? 0.00390625f : 0.0625f;
    float s0 = (j      <= irow) ? d0*0.17677669529663687f - slope*(float)((irow-j)/10)    : -1e30f;
    float s1 = (j + 64 <= irow) ? d1*0.17677669529663687f - slope*(float)((irow-j-64)/10) : -1e30f;
    float m = dpp_max_pos(fmaxf(s0, s1) + 16384.f) - 16384.f;
    float e0 = (j      <= irow) ? __expf(s0 - m) : 0.f;
    float e1 = (j + 64 <= irow) ? __expf(s1 - m) : 0.f;
    float inv = 1.f / dpp_sum(e0 + e1);
    sc[h*128 + j]      = e0*inv;
    sc[h*128 + j + 64] = e1*inv;
  }
  __syncthreads();
  if (tid < 64){
    const float* a = sc + (tid >> 5)*128;
    float a0=0.f,a1=0.f,a2=0.f,a3=0.f;
    #pragma unroll
    for (int jj = 0; jj < 30; ++jj){
      a0 += a[4*jj]   * (float)vp[(4*jj)*64   + tid];
      a1 += a[4*jj+1] * (float)vp[(4*jj+1)*64 + tid];
      a2 += a[4*jj+2] * (float)vp[(4*jj+2)*64 + tid];
      a3 += a[4*jj+3] * (float)vp[(4*jj+3)*64 + tid];
    }
    at[tid] = (a0+a1)+(a2+a3);
  }
  __syncthreads();
  if (tid < 64){
    const u32* orow = (const u32*)(wo_b + tid*64);
    float acc = bo[tid];
    #pragma unroll
    for (int w = 0; w < 32; ++w){ float2 p = bp2(orow[w]); acc += p.x*at[2*w] + p.y*at[2*w+1]; }
    float y = xs[tid] + acc;
    float s = dpp_sum(y), s2 = dpp_sum(y*y);
    float m = s*(1.f/64.f), var = fmaxf(s2*(1.f/64.f) - m*m, 0.f);
    float h1 = (y - m)*rsqrtf(var + 1e-5f)*g1[tid] + be1[tid];
    float z = h1 + cross[irow*64 + tid];
    float sz = dpp_sum(z), sz2 = dpp_sum(z*z);
    float mz = sz*(1.f/64.f), vz = fmaxf(sz2*(1.f/64.f) - mz*mz, 0.f);
    h2s[tid] = (z - mz)*rsqrtf(vz + 1e-5f)*g2[tid] + be2[tid];
  }
  __syncthreads();
  {
    const u32* w1r = (const u32*)(w1_b + tid*64);
    float acc = c1[tid];
    #pragma unroll
    for (int w = 0; w < 32; ++w){ float2 p = bp2(w1r[w]); acc += p.x*h2s[2*w] + p.y*h2s[2*w+1]; }
    fs[tid] = fmaxf(acc, 0.f);
  }
  __syncthreads();
  if (tid < 64){
    const u32* w2r = (const u32*)(w2_b + tid*128);
    float acc = c2[tid];
    #pragma unroll
    for (int w = 0; w < 64; ++w){ float2 p = bp2(w2r[w]); acc += p.x*fs[2*w] + p.y*fs[2*w+1]; }
    float y = h2s[tid] + acc;
    float s = dpp_sum(y), s2 = dpp_sum(y*y);
    float m = s*(1.f/64.f), var = fmaxf(s2*(1.f/64.f) - m*m, 0.f);
    h3s[tid] = (y - m)*rsqrtf(var + 1e-5f)*g3[tid] + be3[tid];
  }
  __syncthreads();
  if (tid < DOUT_){
    const u32* rr = (const u32*)(wr_b + tid*64);
    float acc = br[tid];
    #pragma unroll
    for (int w = 0; w < 32; ++w){ float2 p = bp2(rr[w]); acc += p.x*h3s[2*w] + p.y*h3s[2*w+1]; }
    out[irow*DOUT_ + tid] = acc;
  }
}

extern "C" void kernel_launch(void* const* d_in, const int* in_sizes, int n_in,
                              void* d_out, int out_size, void* d_ws, size_t ws_size,
                              hipStream_t stream){
  const float* audio=(const float*)d_in[0];
  const float* Wa   =(const float*)d_in[1];
  const float* ba   =(const float*)d_in[2];
  const float* objW =(const float*)d_in[3];
  const float* Wq   =(const float*)d_in[4];
  const float* bq   =(const float*)d_in[5];
  const float* Wk   =(const float*)d_in[6];
  const float* bk   =(const float*)d_in[7];
  const float* Wv   =(const float*)d_in[8];
  const float* bv   =(const float*)d_in[9];
  const float* Wo   =(const float*)d_in[10];
  const float* bo   =(const float*)d_in[11];
  const float* Wv2  =(const float*)d_in[12];
  const float* bv2  =(const float*)d_in[13];
  const float* Wo2  =(const float*)d_in[14];
  const float* bo2  =(const float*)d_in[15];
  const float* g1   =(const float*)d_in[16];
  const float* be1  =(const float*)d_in[17];
  const float* g2   =(const float*)d_in[18];
  const float* be2  =(const float*)d_in[19];
  const float* g3   =(const float*)d_in[20];
  const float* be3  =(const float*)d_in[21];
  const float* W1   =(const float*)d_in[22];
  const float* c1   =(const float*)d_in[23];
  const float* W2   =(const float*)d_in[24];
  const float* c2   =(const float*)d_in[25];
  const float* Wr   =(const float*)d_in[26];
  const float* br   =(const float*)d_in[27];
  const float* Wm   =(const float*)d_in[28];
  const float* bm   =(const float*)d_in[29];

  float* ws    = (float*)d_ws;
  float* cross = ws;            // 7680 floats
  float* Ms    = ws + 7680;     // 4096
  float* bMv   = ws + 11776;    // 64
  u16* xw16 = (u16*)(ws + 11840);   // 7680 u16
  u16* Kw16 = xw16 + 7680;
  u16* Vw16 = Kw16 + 7680;
  u16* wo_b = Vw16 + 7680;      // 4096
  u16* w1_b = wo_b + 4096;      // 8192
  u16* w2_b = w1_b + 8192;      // 8192
  u16* wr_b = w2_b + 8192;      // 1984
  float* out = (float*)d_out;

  k_pre  <<<dim3(121), dim3(256), 0, stream>>>(audio, Wa, ba, Wv2, bv2, Wo2, bo2,
                                               Wo, W1, W2, Wr, Wm, br, bm,
                                               cross, Ms, bMv, wo_b, w1_b, w2_b, wr_b);
  k_scan <<<dim3(1),   dim3(128), 0, stream>>>(objW, Wq, bq, Wk, bk, Wv, bv, Wo, bo,
                                               g1, be1, g2, be2, g3, be3,
                                               W1, c1, W2, c2, Ms, bMv,
                                               cross, xw16, Kw16, Vw16);
  k_final<<<dim3(120), dim3(128), 0, stream>>>(Wq, bq, bo, g1, be1, g2, be2, g3, be3,
                                               c1, c2, br, wo_b, w1_b, w2_b, wr_b,
                                               cross, xw16, Kw16, Vw16, out);
}

// Round 4
// 354.346 us; speedup vs baseline: 1.1357x; 1.1357x over previous
//
#include <hip/hip_runtime.h>

typedef unsigned short u16;
typedef unsigned int   u32;
typedef _Float16 f16;
typedef f16 h2 __attribute__((ext_vector_type(2)));
typedef f16 h4 __attribute__((ext_vector_type(4)));
typedef f16 h8 __attribute__((ext_vector_type(8)));

#define T_    120
#define D_    64
#define DOUT_ 31
#define KROW_ 68    // f16/row: 136B, 8B-aligned
#define VROW_ 132   // f16/row: 264B, 8B-aligned

#if defined(__has_builtin)
#if __has_builtin(__builtin_amdgcn_fdot2)
#define DOT2(a,b,c) __builtin_amdgcn_fdot2((a),(b),(c),false)
#endif
#endif
#ifndef DOT2
#define DOT2(a,b,c) ((float)(a).x*(float)(b).x + ((float)(a).y*(float)(b).y + (c)))
#endif
#define SHV(x,i,j) __builtin_shufflevector((x),(x),(i),(j))

__device__ __forceinline__ h2 pk(float a, float b){
#if defined(__has_builtin) && __has_builtin(__builtin_amdgcn_cvt_pkrtz)
  return __builtin_bit_cast(h2, __builtin_amdgcn_cvt_pkrtz(a, b));
#else
  h2 r; r.x = (f16)a; r.y = (f16)b; return r;
#endif
}
__device__ __forceinline__ float b2f(u16 u){ return __uint_as_float(((u32)u) << 16); }
__device__ __forceinline__ float2 bp2(u32 u){
  float2 r; r.x = __uint_as_float(u << 16); r.y = __uint_as_float(u & 0xffff0000u); return r;
}
__device__ __forceinline__ u16 f2bu(float f){
  u32 u = __float_as_uint(f);
  u32 r = u + 0x7fffu + ((u >> 16) & 1u);
  return (u16)(r >> 16);
}
__device__ __forceinline__ u16 f2h16(float x){
  f16 v = (f16)x; u16 r; __builtin_memcpy(&r, &v, 2); return r;
}
__device__ __forceinline__ float fast_rcp(float x){
#if defined(__has_builtin) && __has_builtin(__builtin_amdgcn_rcpf)
  return __builtin_amdgcn_rcpf(x);
#else
  return 1.f / x;
#endif
}
#define WSYNC() do{ __asm__ __volatile__("" ::: "memory"); __builtin_amdgcn_wave_barrier(); }while(0)

__device__ __forceinline__ float dpp_sum(float x){
  int t;
  t = __builtin_amdgcn_update_dpp(0, __float_as_int(x), 0x111, 0xf, 0xf, true); x += __int_as_float(t);
  t = __builtin_amdgcn_update_dpp(0, __float_as_int(x), 0x112, 0xf, 0xf, true); x += __int_as_float(t);
  t = __builtin_amdgcn_update_dpp(0, __float_as_int(x), 0x114, 0xf, 0xf, true); x += __int_as_float(t);
  t = __builtin_amdgcn_update_dpp(0, __float_as_int(x), 0x118, 0xf, 0xf, true); x += __int_as_float(t);
  t = __builtin_amdgcn_update_dpp(0, __float_as_int(x), 0x142, 0xf, 0xf, true); x += __int_as_float(t);
  t = __builtin_amdgcn_update_dpp(0, __float_as_int(x), 0x143, 0xf, 0xf, true); x += __int_as_float(t);
  return __int_as_float(__builtin_amdgcn_readlane(__float_as_int(x), 63));
}
__device__ __forceinline__ float dpp_max_pos(float x){   // requires true max > 0
  int t;
  t = __builtin_amdgcn_update_dpp(0, __float_as_int(x), 0x111, 0xf, 0xf, true); x = fmaxf(x, __int_as_float(t));
  t = __builtin_amdgcn_update_dpp(0, __float_as_int(x), 0x112, 0xf, 0xf, true); x = fmaxf(x, __int_as_float(t));
  t = __builtin_amdgcn_update_dpp(0, __float_as_int(x), 0x114, 0xf, 0xf, true); x = fmaxf(x, __int_as_float(t));
  t = __builtin_amdgcn_update_dpp(0, __float_as_int(x), 0x118, 0xf, 0xf, true); x = fmaxf(x, __int_as_float(t));
  t = __builtin_amdgcn_update_dpp(0, __float_as_int(x), 0x142, 0xf, 0xf, true); x = fmaxf(x, __int_as_float(t));
  t = __builtin_amdgcn_update_dpp(0, __float_as_int(x), 0x143, 0xf, 0xf, true); x = fmaxf(x, __int_as_float(t));
  return __int_as_float(__builtin_amdgcn_readlane(__float_as_int(x), 63));
}
__device__ __forceinline__ float pe_val(int row, int i){
  const float coef = -0.28782313662425574f; // -ln(10000)/32
  int p = row % 10;
  float dv  = __expf((float)(i >> 1) * coef);
  float ang = (float)p * dv;
  return (i & 1) ? __cosf(ang) : __sinf(ang);
}
__device__ __forceinline__ void loadrow32(h2* dst, const float* row){
  #pragma unroll
  for (int r = 0; r < 16; ++r){
    float4 f = ((const float4*)row)[r];
    dst[2*r]   = pk(f.x, f.y);
    dst[2*r+1] = pk(f.z, f.w);
  }
}
__device__ __forceinline__ void loadrow16(h2* dst, const float* row){   // 32 floats
  #pragma unroll
  for (int r = 0; r < 8; ++r){
    float4 f = ((const float4*)row)[r];
    dst[2*r]   = pk(f.x, f.y);
    dst[2*r+1] = pk(f.z, f.w);
  }
}

// ---------- kernel PRE: blocks 0-119: mem+cross; block 120: bf16 prep + M=Wm@Wr fusion ----------
__global__ __launch_bounds__(256) void k_pre(const float* __restrict__ audio,
                                             const float* __restrict__ Wa, const float* __restrict__ ba,
                                             const float* __restrict__ Wv2, const float* __restrict__ bv2,
                                             const float* __restrict__ Wo2, const float* __restrict__ bo2,
                                             const float* __restrict__ Wo, const float* __restrict__ W1,
                                             const float* __restrict__ W2, const float* __restrict__ Wr,
                                             const float* __restrict__ Wm, const float* __restrict__ br,
                                             const float* __restrict__ bm,
                                             float* __restrict__ cross, float* __restrict__ Ms,
                                             float* __restrict__ bMv,
                                             u16* __restrict__ wob, u16* __restrict__ w1b,
                                             u16* __restrict__ w2b, u16* __restrict__ wrb){
  const int b = blockIdx.x, tid = threadIdx.x;
  if (b == 120){
    for (int i = tid; i < 4096; i += 256) wob[i] = f2bu(Wo[i]);
    for (int i = tid; i < 8192; i += 256){ w1b[i] = f2bu(W1[i]); w2b[i] = f2bu(W2[i]); }
    for (int i = tid; i < 1984; i += 256) wrb[i] = f2bu(Wr[i]);
    for (int idx = tid; idx < 4096; idx += 256){
      int d = idx >> 6, e = idx & 63;
      float acc = 0.f;
      #pragma unroll
      for (int j = 0; j < 31; ++j) acc += Wm[d*31 + j] * Wr[j*64 + e];
      Ms[idx] = acc;
    }
    if (tid < 64){
      float acc = bm[tid];
      #pragma unroll
      for (int j = 0; j < 31; ++j) acc += Wm[tid*31 + j] * br[j];
      bMv[tid] = acc;
    }
    return;
  }
  __shared__ float ash[1024];
  __shared__ float msh[64], tsh[64];
  for (int i = tid; i < 1024; i += 256) ash[i] = audio[b*1024 + i];
  __syncthreads();
  const int w = tid >> 6, lane = tid & 63;
  for (int d = w*16; d < w*16 + 16; ++d){
    const float4* row = (const float4*)(Wa + d*1024);
    float acc = 0.f;
    #pragma unroll
    for (int m = 0; m < 4; ++m){
      float4 wp = row[lane + 64*m];
      int j = 4*(lane + 64*m);
      acc += wp.x*ash[j] + wp.y*ash[j+1] + wp.z*ash[j+2] + wp.w*ash[j+3];
    }
    acc = dpp_sum(acc);
    if (lane == 0) msh[d] = acc + ba[d];
  }
  __syncthreads();
  if (tid < 64){
    const float4* r1 = (const float4*)(Wv2 + tid*64);
    float a = bv2[tid];
    #pragma unroll
    for (int j = 0; j < 16; ++j){ float4 p = r1[j]; a += p.x*msh[4*j] + p.y*msh[4*j+1] + p.z*msh[4*j+2] + p.w*msh[4*j+3]; }
    tsh[tid] = a;
  }
  __syncthreads();
  if (tid < 64){
    const float4* r2 = (const float4*)(Wo2 + tid*64);
    float c = bo2[tid];
    #pragma unroll
    for (int j = 0; j < 16; ++j){ float4 p = r2[j]; c += p.x*tsh[4*j] + p.y*tsh[4*j+1] + p.z*tsh[4*j+2] + p.w*tsh[4*j+3]; }
    cross[b*64 + tid] = c;
  }
}

// ---------- kernel SCAN: head-symmetric waves, redundant scalar compute, 2 barriers/iter ----------
// Wave h owns head h end-to-end (q/k/v halves, private sch, K/V column-halves, PV, Wo-block
// partial). Serial segments (LN1/LN2, y3/LN3/M-dot, x-update) computed redundantly on BOTH
// waves from published f32 partials -> identical values, benign same-value LDS races,
// intra-wave WSYNC ordering only. Cross-wave exchange only at:
//   B1: saP_h = inv_h * (Wo[:,h-block] . at_h)      (heads mixed by Wo)
//   B2: pP_h  = W2[:,h-half] . fs_h                 (FFN halves mixed by W2)
__global__ __launch_bounds__(128, 1) void k_scan(
    const float* __restrict__ objW,
    const float* __restrict__ Wq, const float* __restrict__ bq,
    const float* __restrict__ Wk, const float* __restrict__ bk,
    const float* __restrict__ Wv, const float* __restrict__ bv,
    const float* __restrict__ Wo, const float* __restrict__ bo,
    const float* __restrict__ g1, const float* __restrict__ be1,
    const float* __restrict__ g2, const float* __restrict__ be2,
    const float* __restrict__ g3, const float* __restrict__ be3,
    const float* __restrict__ W1, const float* __restrict__ c1,
    const float* __restrict__ W2, const float* __restrict__ c2,
    const float* __restrict__ Ms, const float* __restrict__ bMv,
    const float* __restrict__ cross,
    u16* __restrict__ xw16, u16* __restrict__ Kw16, u16* __restrict__ Vw16)
{
  __shared__ __align__(16) f16 KcS[128*KROW_];   // rows 119..127 stay zero
  __shared__ __align__(16) f16 VcS[D_*VROW_];    // cols 120..131 stay zero
  __shared__ __align__(16) f16 xwS[T_*D_];       // x history (f16)
  __shared__ __align__(16) f16 sch[256];         // [head][128] exp-scores (private per wave)
  __shared__ __align__(16) f16 xh[64], qh[64], h2h[64], h3h[64];
  __shared__ __align__(16) f16 at0h[32], at1h[32];
  __shared__ __align__(16) f16 fsh[128];
  __shared__ float saP0[64], saP1[64];           // per-head Wo partials (inv folded)
  __shared__ float pP0[64], pP1[64];             // per-half FFN2 partials
  __shared__ float pe_tab[640];

  const int tid = threadIdx.x;
  const int i = tid & 63;
  const int hh = tid >> 6;      // wave index == head index
  const bool w1w = hh != 0;

  // register weights per wave h:
  //  A[32] = (i<32 ? Wq row h*32+i : Wk row h*32+(i-32))
  //  B[32] = Wv row h*32+(i&31)          (used by lanes<32)
  //  C[16] = Wo[i][h*32 : h*32+32]
  //  D[32] = W1 row (h*64+i)
  //  G[32] = W2[i][h*64 : h*64+64]
  //  E[32] = (Ms.*g3) row i
  h2 A[32], B[32], C[16], D[32], G[32], E[32];
  float biasA=0.f, biasB=0.f, bo_r=0.f, c1r=0.f, c2_r=0.f, cls_r=0.f;
  float g1r=0.f,b1r=0.f,g2r=0.f,b2r=0.f;
  float mg_r=0.f, u_r=0.f;
  float x_r;                    // both waves: x_t (lane i holds x_i)

  {
    const int qi = hh*32 + (i & 31);
    if (i < 32){ loadrow32(A, Wq + qi*64); biasA = bq[qi]; }
    else       { loadrow32(A, Wk + qi*64); biasA = bk[qi]; }
    loadrow32(B, Wv + qi*64);  biasB = bv[qi];
    loadrow16(C, Wo + i*64 + hh*32);
    loadrow32(D, W1 + (hh*64 + i)*64);
    loadrow32(G, W2 + i*128 + hh*64);
    {
      const float4* mr  = (const float4*)(Ms + i*64);
      const float4* gv  = (const float4*)g3;
      const float4* b3v = (const float4*)be3;
      float mg = 0.f, mb = 0.f;
      #pragma unroll
      for (int r = 0; r < 16; ++r){
        float4 f = mr[r], g = gv[r], b = b3v[r];
        float e0 = f.x*g.x, e1 = f.y*g.y, e2 = f.z*g.z, e3 = f.w*g.w;
        E[2*r]   = pk(e0, e1);
        E[2*r+1] = pk(e2, e3);
        mg += (e0+e1)+(e2+e3);
        mb += f.x*b.x + f.y*b.y + f.z*b.z + f.w*b.w;
      }
      mg_r = mg;
      u_r  = bMv[i] + objW[i*5] + mb;
    }
    c1r = c1[hh*64 + i]; c2_r = c2[i]; bo_r = bo[i];
    g1r = g1[i]; b1r = be1[i]; g2r = g2[i]; b2r = be2[i];
    cls_r = cross[119*64 + i];
  }
  { u32* p = (u32*)KcS; for (int idx = tid; idx < 128*KROW_/2; idx += 128) p[idx] = 0; }
  { u32* p = (u32*)VcS; for (int idx = tid; idx < D_*VROW_/2;  idx += 128) p[idx] = 0; }
  for (int idx = tid; idx < 640; idx += 128) pe_tab[idx] = pe_val(idx >> 6, idx & 63);
  {
    float x0 = objW[i*5] + pe_val(0, i);
    x_r = x0;
    xh[i] = (f16)x0;            // both waves, identical value (benign)
    if (w1w) xwS[i] = (f16)x0;
  }
  __syncthreads();

  int pp = 1;  // (t+1) % 10
  const float slope = hh ? 0.00390625f : 0.0625f;
  for (int t = 0; t < T_-1; ++t){
    float e0r, e1r;
    h8 xr[8];
    // ---- P1 (intra): q-half (lanes<32) | k-half (lanes>=32) for own head ----
    {
      const h8* xv = (const h8*)xh;
      #pragma unroll
      for (int r = 0; r < 8; ++r) xr[r] = xv[r];
      float a0=biasA,a1=0.f,a2=0.f,a3=0.f;
      #pragma unroll
      for (int r = 0; r < 8; ++r){
        h8 x = xr[r];
        a0 = DOT2(A[4*r+0], SHV(x,0,1), a0);
        a1 = DOT2(A[4*r+1], SHV(x,2,3), a1);
        a2 = DOT2(A[4*r+2], SHV(x,4,5), a2);
        a3 = DOT2(A[4*r+3], SHV(x,6,7), a3);
      }
      float qk = (a0+a1)+(a2+a3);
      f16* dst = (i < 32) ? (qh + hh*32 + i) : (KcS + t*KROW_ + hh*32 + (i - 32));
      *dst = (f16)qk;
    }
    WSYNC();
    // ---- P2 (intra): v (lanes<32, own head dims) ; scores + exp (all lanes) ----
    {
      if (i < 32){
        float v0=biasB,v1=0.f,v2=0.f,v3=0.f;
        #pragma unroll
        for (int r = 0; r < 8; ++r){
          h8 x = xr[r];
          v0 = DOT2(B[4*r+0], SHV(x,0,1), v0); v1 = DOT2(B[4*r+1], SHV(x,2,3), v1);
          v2 = DOT2(B[4*r+2], SHV(x,4,5), v2); v3 = DOT2(B[4*r+3], SHV(x,6,7), v3);
        }
        VcS[(hh*32 + i)*VROW_ + t] = (f16)((v0+v1)+(v2+v3));
      }
      const int j = i;
      const h8* qv = (const h8*)(qh + hh*32);
      const h4* k0 = (const h4*)(KcS + j*KROW_ + hh*32);
      const h4* k1 = (const h4*)(KcS + (j+64)*KROW_ + hh*32);
      float d0a=0.f,d0b=0.f,d1a=0.f,d1b=0.f;
      #pragma unroll
      for (int r = 0; r < 4; ++r){
        h8 q = qv[r];
        h4 ka = k0[2*r], kb = k0[2*r+1], kc = k1[2*r], kd = k1[2*r+1];
        d0a = DOT2(SHV(ka,0,1), SHV(q,0,1), d0a);
        d0b = DOT2(SHV(ka,2,3), SHV(q,2,3), d0b);
        d0a = DOT2(SHV(kb,0,1), SHV(q,4,5), d0a);
        d0b = DOT2(SHV(kb,2,3), SHV(q,6,7), d0b);
        d1a = DOT2(SHV(kc,0,1), SHV(q,0,1), d1a);
        d1b = DOT2(SHV(kc,2,3), SHV(q,2,3), d1b);
        d1a = DOT2(SHV(kd,0,1), SHV(q,4,5), d1a);
        d1b = DOT2(SHV(kd,2,3), SHV(q,6,7), d1b);
      }
      float d0 = d0a + d0b, d1 = d1a + d1b;
      int r0 = (t - j) / 10, r1 = (t - j - 64) / 10;
      float s0 = d0*0.17677669529663687f - slope*(float)r0;
      float s1 = d1*0.17677669529663687f - slope*(float)r1;
      e0r = (j      <= t) ? __expf(fminf(s0, 8.f)) : 0.f;
      e1r = (j + 64 <= t) ? __expf(fminf(s1, 8.f)) : 0.f;
      sch[hh*128 + j]      = (f16)e0r;
      sch[hh*128 + j + 64] = (f16)e1r;
    }
    WSYNC();
    // ---- P3 (intra): denom+inv ; PV (pos split across lane pairs) ; Wo-block partial ----
    {
      float den = dpp_sum(e0r + e1r);
      float inv_w = fast_rcp(den);
      const int l5 = i & 31;
      const int d  = hh*32 + l5;
      const int co = (i & 32) ? 64 : 0;     // position-half offset
      const h8* av = (const h8*)(sch + hh*128 + co);
      const h4* vv = (const h4*)(VcS + d*VROW_ + co);
      float p0=0.f,p1=0.f,p2=0.f,p3=0.f;
      #pragma unroll
      for (int r = 0; r < 8; ++r){
        h8 a = av[r];
        h4 va = vv[2*r], vb = vv[2*r+1];
        p0 = DOT2(SHV(va,0,1), SHV(a,0,1), p0);
        p1 = DOT2(SHV(va,2,3), SHV(a,2,3), p1);
        p2 = DOT2(SHV(vb,0,1), SHV(a,4,5), p2);
        p3 = DOT2(SHV(vb,2,3), SHV(a,6,7), p3);
      }
      float p = (p0+p1)+(p2+p3);
      p += __shfl_xor(p, 32, 64);           // combine position halves (lane pairs)
      f16* ath = hh ? at1h : at0h;
      ath[l5] = (f16)p;                     // lanes l and l+32 write same value (benign)
      WSYNC();
      const h8* pv = (const h8*)ath;        // 32 f16 = 4 h8
      float w0a=0.f,w1a=0.f,w2a=0.f,w3a=0.f;
      #pragma unroll
      for (int r = 0; r < 4; ++r){
        h8 x = pv[r];
        w0a = DOT2(C[4*r+0], SHV(x,0,1), w0a);
        w1a = DOT2(C[4*r+1], SHV(x,2,3), w1a);
        w2a = DOT2(C[4*r+2], SHV(x,4,5), w2a);
        w3a = DOT2(C[4*r+3], SHV(x,6,7), w3a);
      }
      float* saP = hh ? saP1 : saP0;
      saP[i] = inv_w * ((w0a+w1a)+(w2a+w3a));
    }
    __syncthreads();   // B1: exchange head partials
    // ---- P4 (redundant both waves): sa -> LN1 -> +cross -> LN2 ; FFN1-half ; FFN2-part ----
    float h2v;
    {
      float sa = bo_r + saP0[i] + saP1[i];
      float y = x_r + sa;
      float s = dpp_sum(y), s2 = dpp_sum(y*y);
      float m = s*(1.f/64.f), var = fmaxf(s2*(1.f/64.f) - m*m, 0.f);
      float h1 = (y - m)*rsqrtf(var + 1e-5f)*g1r + b1r;
      float z = h1 + cls_r;
      float sz = dpp_sum(z), sz2 = dpp_sum(z*z);
      float mz = sz*(1.f/64.f), vz = fmaxf(sz2*(1.f/64.f) - mz*mz, 0.f);
      h2v = (z - mz)*rsqrtf(vz + 1e-5f)*g2r + b2r;
      h2h[i] = (f16)h2v;                    // both waves, identical value
      WSYNC();
      const h8* hv = (const h8*)h2h;
      float a0=c1r, a1=0.f, a2=0.f, a3=0.f;
      #pragma unroll
      for (int r = 0; r < 8; ++r){
        h8 x = hv[r];
        a0 = DOT2(D[4*r+0], SHV(x,0,1), a0);
        a1 = DOT2(D[4*r+1], SHV(x,2,3), a1);
        a2 = DOT2(D[4*r+2], SHV(x,4,5), a2);
        a3 = DOT2(D[4*r+3], SHV(x,6,7), a3);
      }
      fsh[hh*64 + i] = (f16)fmaxf((a0+a1)+(a2+a3), 0.f);
      WSYNC();
      const h8* fv = (const h8*)(fsh + hh*64);
      float f0=0.f, f1=0.f, f2=0.f, f3=0.f;
      #pragma unroll
      for (int r = 0; r < 8; ++r){
        h8 x = fv[r];
        f0 = DOT2(G[4*r+0], SHV(x,0,1), f0);
        f1 = DOT2(G[4*r+1], SHV(x,2,3), f1);
        f2 = DOT2(G[4*r+2], SHV(x,4,5), f2);
        f3 = DOT2(G[4*r+3], SHV(x,6,7), f3);
      }
      float* pP = hh ? pP1 : pP0;
      pP[i] = (f0+f1)+(f2+f3);
    }
    __syncthreads();   // B2: exchange FFN halves
    // ---- P5 (redundant both waves): y3 ; LN3 folded into M' matvec ; x_{t+1} ----
    {
      float y3 = h2v + c2_r + pP0[i] + pP1[i];
      h3h[i] = (f16)y3;                     // both waves, identical value
      WSYNC();
      const h8* yv3 = (const h8*)h3h;
      h8 yr[8];
      #pragma unroll
      for (int r = 0; r < 8; ++r) yr[r] = yv3[r];
      float s3 = dpp_sum(y3), s32 = dpp_sum(y3*y3);
      float m3 = s3*(1.f/64.f), v3 = fmaxf(s32*(1.f/64.f) - m3*m3, 0.f);
      float invs = rsqrtf(v3 + 1e-5f);
      float m0=0.f, m1=0.f, m2=0.f, mm3=0.f;
      #pragma unroll
      for (int r = 0; r < 8; ++r){
        h8 x = yr[r];
        m0 = DOT2(E[4*r+0], SHV(x,0,1), m0);
        m1 = DOT2(E[4*r+1], SHV(x,2,3), m1);
        m2 = DOT2(E[4*r+2], SHV(x,4,5), m2);
        mm3 = DOT2(E[4*r+3], SHV(x,6,7), mm3);
      }
      float xn = ((m0+m1)+(m2+mm3))*invs + (u_r - m3*invs*mg_r) + pe_tab[pp*64 + i];
      x_r = xn;
      xh[i] = (f16)xn;                      // both waves, identical value
      if (w1w) xwS[(t+1)*64 + i] = (f16)xn;
    }
    WSYNC();
    pp = (pp == 9) ? 0 : pp + 1;
  }
  // ---- epilogue: k,v for row 119 directly to global f16 (head-halves) ----
  {
    const h8* xv = (const h8*)xh;
    h8 xr[8];
    #pragma unroll
    for (int r = 0; r < 8; ++r) xr[r] = xv[r];
    if (i < 32){
      float v0=biasB,v1=0.f,v2=0.f,v3=0.f;
      #pragma unroll
      for (int r = 0; r < 8; ++r){
        h8 x = xr[r];
        v0 = DOT2(B[4*r+0], SHV(x,0,1), v0);
        v1 = DOT2(B[4*r+1], SHV(x,2,3), v1);
        v2 = DOT2(B[4*r+2], SHV(x,4,5), v2);
        v3 = DOT2(B[4*r+3], SHV(x,6,7), v3);
      }
      Vw16[119*64 + hh*32 + i] = f2h16((v0+v1)+(v2+v3));
    } else {
      float k0=biasA,k1=0.f,k2=0.f,k3=0.f;
      #pragma unroll
      for (int r = 0; r < 8; ++r){
        h8 x = xr[r];
        k0 = DOT2(A[4*r+0], SHV(x,0,1), k0);
        k1 = DOT2(A[4*r+1], SHV(x,2,3), k1);
        k2 = DOT2(A[4*r+2], SHV(x,4,5), k2);
        k3 = DOT2(A[4*r+3], SHV(x,6,7), k3);
      }
      Kw16[119*64 + hh*32 + (i-32)] = f2h16((k0+k1)+(k2+k3));
    }
  }
  __syncthreads();   // K/V/x halves from both waves must be visible for the dump
  // ---- dump LDS histories (rows 0..118 K/V, all x) ----
  {
    const u16* kc = (const u16*)KcS;
    const u16* vc = (const u16*)VcS;
    for (int idx = tid; idx < 119*64; idx += 128){
      int t_ = idx >> 6, d = idx & 63;
      Kw16[idx] = kc[t_*KROW_ + d];
      Vw16[idx] = vc[d*VROW_ + t_];
    }
    const u32* xs32 = (const u32*)xwS;
    for (int idx = tid; idx < T_*D_/2; idx += 128) ((u32*)xw16)[idx] = xs32[idx];
  }
}

// ---------- kernel FINAL: full pass, one block per row (f16 x/K/V inputs) ----------
__global__ __launch_bounds__(128) void k_final(
    const float* __restrict__ Wq, const float* __restrict__ bq, const float* __restrict__ bo,
    const float* __restrict__ g1, const float* __restrict__ be1,
    const float* __restrict__ g2, const float* __restrict__ be2,
    const float* __restrict__ g3, const float* __restrict__ be3,
    const float* __restrict__ c1, const float* __restrict__ c2, const float* __restrict__ br,
    const u16* __restrict__ wo_b, const u16* __restrict__ w1_b,
    const u16* __restrict__ w2_b, const u16* __restrict__ wr_b,
    const float* __restrict__ cross, const u16* __restrict__ xw16,
    const u16* __restrict__ Kw16, const u16* __restrict__ Vw16,
    float* __restrict__ out)
{
  __shared__ float xs[64], qs[64], at[64], h2s[64], h3s[64], fs[128], sc[256];
  const int irow = blockIdx.x, tid = threadIdx.x;
  const f16* xp = (const f16*)xw16;
  const f16* kp = (const f16*)Kw16;
  const f16* vp = (const f16*)Vw16;
  if (tid < 64) xs[tid] = (float)xp[irow*64 + tid];
  __syncthreads();
  if (tid < 64){
    const float4* wr_ = (const float4*)(Wq + tid*64);
    float acc = bq[tid];
    #pragma unroll
    for (int j = 0; j < 16; ++j){ float4 w = wr_[j]; acc += w.x*xs[4*j] + w.y*xs[4*j+1] + w.z*xs[4*j+2] + w.w*xs[4*j+3]; }
    qs[tid] = acc;
  }
  __syncthreads();
  {
    const int h = tid >> 6, j = tid & 63;
    const float* qh_ = qs + h*32;
    float d0 = 0.f, d1 = 0.f;
    const h4* k0 = (const h4*)(kp + j*64 + h*32);
    #pragma unroll
    for (int w = 0; w < 8; ++w){
      h4 p = k0[w];
      d0 += (float)p.x*qh_[4*w] + (float)p.y*qh_[4*w+1] + (float)p.z*qh_[4*w+2] + (float)p.w*qh_[4*w+3];
    }
    if (j < 56){
      const h4* k1 = (const h4*)(kp + (j+64)*64 + h*32);
      #pragma unroll
      for (int w = 0; w < 8; ++w){
        h4 p = k1[w];
        d1 += (float)p.x*qh_[4*w] + (float)p.y*qh_[4*w+1] + (float)p.z*qh_[4*w+2] + (float)p.w*qh_[4*w+3];
      }
    }
    const float slope = h ? 0.00390625f : 0.0625f;
    float s0 = (j      <= irow) ? d0*0.17677669529663687f - slope*(float)((irow-j)/10)    : -1e30f;
    float s1 = (j + 64 <= irow) ? d1*0.17677669529663687f - slope*(float)((irow-j-64)/10) : -1e30f;
    float m = dpp_max_pos(fmaxf(s0, s1) + 16384.f) - 16384.f;
    float e0 = (j      <= irow) ? __expf(s0 - m) : 0.f;
    float e1 = (j + 64 <= irow) ? __expf(s1 - m) : 0.f;
    float inv = 1.f / dpp_sum(e0 + e1);
    sc[h*128 + j]      = e0*inv;
    sc[h*128 + j + 64] = e1*inv;
  }
  __syncthreads();
  if (tid < 64){
    const float* a = sc + (tid >> 5)*128;
    float a0=0.f,a1=0.f,a2=0.f,a3=0.f;
    #pragma unroll
    for (int jj = 0; jj < 30; ++jj){
      a0 += a[4*jj]   * (float)vp[(4*jj)*64   + tid];
      a1 += a[4*jj+1] * (float)vp[(4*jj+1)*64 + tid];
      a2 += a[4*jj+2] * (float)vp[(4*jj+2)*64 + tid];
      a3 += a[4*jj+3] * (float)vp[(4*jj+3)*64 + tid];
    }
    at[tid] = (a0+a1)+(a2+a3);
  }
  __syncthreads();
  if (tid < 64){
    const u32* orow = (const u32*)(wo_b + tid*64);
    float acc = bo[tid];
    #pragma unroll
    for (int w = 0; w < 32; ++w){ float2 p = bp2(orow[w]); acc += p.x*at[2*w] + p.y*at[2*w+1]; }
    float y = xs[tid] + acc;
    float s = dpp_sum(y), s2 = dpp_sum(y*y);
    float m = s*(1.f/64.f), var = fmaxf(s2*(1.f/64.f) - m*m, 0.f);
    float h1 = (y - m)*rsqrtf(var + 1e-5f)*g1[tid] + be1[tid];
    float z = h1 + cross[irow*64 + tid];
    float sz = dpp_sum(z), sz2 = dpp_sum(z*z);
    float mz = sz*(1.f/64.f), vz = fmaxf(sz2*(1.f/64.f) - mz*mz, 0.f);
    h2s[tid] = (z - mz)*rsqrtf(vz + 1e-5f)*g2[tid] + be2[tid];
  }
  __syncthreads();
  {
    const u32* w1r = (const u32*)(w1_b + tid*64);
    float acc = c1[tid];
    #pragma unroll
    for (int w = 0; w < 32; ++w){ float2 p = bp2(w1r[w]); acc += p.x*h2s[2*w] + p.y*h2s[2*w+1]; }
    fs[tid] = fmaxf(acc, 0.f);
  }
  __syncthreads();
  if (tid < 64){
    const u32* w2r = (const u32*)(w2_b + tid*128);
    float acc = c2[tid];
    #pragma unroll
    for (int w = 0; w < 64; ++w){ float2 p = bp2(w2r[w]); acc += p.x*fs[2*w] + p.y*fs[2*w+1]; }
    float y = h2s[tid] + acc;
    float s = dpp_sum(y), s2 = dpp_sum(y*y);
    float m = s*(1.f/64.f), var = fmaxf(s2*(1.f/64.f) - m*m, 0.f);
    h3s[tid] = (y - m)*rsqrtf(var + 1e-5f)*g3[tid] + be3[tid];
  }
  __syncthreads();
  if (tid < DOUT_){
    const u32* rr = (const u32*)(wr_b + tid*64);
    float acc = br[tid];
    #pragma unroll
    for (int w = 0; w < 32; ++w){ float2 p = bp2(rr[w]); acc += p.x*h3s[2*w] + p.y*h3s[2*w+1]; }
    out[irow*DOUT_ + tid] = acc;
  }
}

extern "C" void kernel_launch(void* const* d_in, const int* in_sizes, int n_in,
                              void* d_out, int out_size, void* d_ws, size_t ws_size,
                              hipStream_t stream){
  const float* audio=(const float*)d_in[0];
  const float* Wa   =(const float*)d_in[1];
  const float* ba   =(const float*)d_in[2];
  const float* objW =(const float*)d_in[3];
  const float* Wq   =(const float*)d_in[4];
  const float* bq   =(const float*)d_in[5];
  const float* Wk   =(const float*)d_in[6];
  const float* bk   =(const float*)d_in[7];
  const float* Wv   =(const float*)d_in[8];
  const float* bv   =(const float*)d_in[9];
  const float* Wo   =(const float*)d_in[10];
  const float* bo   =(const float*)d_in[11];
  const float* Wv2  =(const float*)d_in[12];
  const float* bv2  =(const float*)d_in[13];
  const float* Wo2  =(const float*)d_in[14];
  const float* bo2  =(const float*)d_in[15];
  const float* g1   =(const float*)d_in[16];
  const float* be1  =(const float*)d_in[17];
  const float* g2   =(const float*)d_in[18];
  const float* be2  =(const float*)d_in[19];
  const float* g3   =(const float*)d_in[20];
  const float* be3  =(const float*)d_in[21];
  const float* W1   =(const float*)d_in[22];
  const float* c1   =(const float*)d_in[23];
  const float* W2   =(const float*)d_in[24];
  const float* c2   =(const float*)d_in[25];
  const float* Wr   =(const float*)d_in[26];
  const float* br   =(const float*)d_in[27];
  const float* Wm   =(const float*)d_in[28];
  const float* bm   =(const float*)d_in[29];

  float* ws    = (float*)d_ws;
  float* cross = ws;            // 7680 floats
  float* Ms    = ws + 7680;     // 4096
  float* bMv   = ws + 11776;    // 64
  u16* xw16 = (u16*)(ws + 11840);   // 7680 u16
  u16* Kw16 = xw16 + 7680;
  u16* Vw16 = Kw16 + 7680;
  u16* wo_b = Vw16 + 7680;      // 4096
  u16* w1_b = wo_b + 4096;      // 8192
  u16* w2_b = w1_b + 8192;      // 8192
  u16* wr_b = w2_b + 8192;      // 1984
  float* out = (float*)d_out;

  k_pre  <<<dim3(121), dim3(256), 0, stream>>>(audio, Wa, ba, Wv2, bv2, Wo2, bo2,
                                               Wo, W1, W2, Wr, Wm, br, bm,
                                               cross, Ms, bMv, wo_b, w1_b, w2_b, wr_b);
  k_scan <<<dim3(1),   dim3(128), 0, stream>>>(objW, Wq, bq, Wk, bk, Wv, bv, Wo, bo,
                                               g1, be1, g2, be2, g3, be3,
                                               W1, c1, W2, c2, Ms, bMv,
                                               cross, xw16, Kw16, Vw16);
  k_final<<<dim3(120), dim3(128), 0, stream>>>(Wq, bq, bo, g1, be1, g2, be2, g3, be3,
                                               c1, c2, br, wo_b, w1_b, w2_b, wr_b,
                                               cross, xw16, Kw16, Vw16, out);
}